// Round 11
// baseline (114.298 us; speedup 1.0000x reference)
//
#include <hip/hip_runtime.h>

// Problem constants (from reference)
constexpr int BATCH = 16384;
constexpr int NN    = 4096;    // NUM_NEURONS
constexpr int BS    = 32;      // BLOCK_SIZE
constexpr int NB    = NN / BS; // 128 blocks

constexpr int THREADS     = 256;   // 4 waves
constexpr int NBLK        = 4;     // blocks per WG -> 512-B contiguous span/row
constexpr int COLS        = BS * NBLK;               // 128
constexpr int ROWS_PER_WG = 256;
constexpr int ROWS_PER_IT = 64;    // 4 waves x 16 rows
constexpr int ITERS       = ROWS_PER_WG / ROWS_PER_IT; // 4
constexpr int COLGROUPS   = NB / NBLK;               // 32
constexpr int ROWTILES    = BATCH / ROWS_PER_WG;     // 64

typedef float f32x4 __attribute__((ext_vector_type(4)));
typedef float f32x2 __attribute__((ext_vector_type(2)));

// Lane layout: r = lane>>2 (16 rows/wave), q = lane&3.
// w[j] = v[row, 16j+4q .. 16j+4q+3], j=0..7  (512 B of the row, quad-dense).
// Block b (0..3), kk (0..31): v-col 32b+kk = w[2b+(kk>>4)][kk&3] of quad-lane
// (kk>>2)&3 -> quad_perm DPP broadcast (VALU pipe, zero DS traffic).
// A-reads: 2 broadcast ds_read_b128 per (b,kk) (4 distinct 16-B addrs,
// 16-way broadcast, conflict-free). Blocks run SEQUENTIALLY per iteration so
// acc stays 8 regs (VGPR control).
//
// Hard-won rules: ALWAYS __launch_bounds__(THREADS) with no min-waves arg
// (R5/R7/R8 spills); sched_barrier(0) every 4 k-steps to cap ds_read-dest
// hoisting (R9: 256 VGPR without it).

template <int S>
__device__ __forceinline__ float qbcast(float x) {
    return __int_as_float(__builtin_amdgcn_update_dpp(
        0, __float_as_int(x), S * 0x55, 0xF, 0xF, true));
}

template <int B, int KK>
struct KStep {
    static __device__ __forceinline__ void run(const f32x4* __restrict__ w,
                                               const float* __restrict__ Alds,
                                               int q, float* __restrict__ acc) {
        constexpr int j = 2 * B + (KK >> 4);
        constexpr int e = KK & 3;
        constexpr int s = (KK >> 2) & 3;     // source lane within quad
        const float vk = qbcast<s>(w[j][e]);
        const float* Ab = Alds + (B * 32 + KK) * 32;
        const f32x4 a0 = *reinterpret_cast<const f32x4*>(Ab + q * 4);
        const f32x4 a1 = *reinterpret_cast<const f32x4*>(Ab + q * 4 + 16);
#pragma unroll
        for (int t = 0; t < 4; ++t) {
            acc[t]     = fmaf(vk, a0[t], acc[t]);
            acc[4 + t] = fmaf(vk, a1[t], acc[4 + t]);
        }
        if constexpr ((KK & 3) == 3) __builtin_amdgcn_sched_barrier(0);
        KStep<B, KK + 1>::run(w, Alds, q, acc);
    }
};
template <int B>
struct KStep<B, BS> {
    static __device__ __forceinline__ void run(const f32x4* __restrict__,
                                               const float* __restrict__, int,
                                               float* __restrict__) {}
};

template <int B>
__device__ __forceinline__ void do_block(const f32x4* __restrict__ w,
                                         const float* __restrict__ Alds,
                                         const float* __restrict__ Blds,
                                         int q, f32x2 dd, float bias,
                                         float* __restrict__ out, size_t rbw) {
    float acc[8] = {};
    KStep<B, 0>::run(w, Alds, q, acc);
#pragma unroll
    for (int h = 0; h < 2; ++h) {
        const int c0 = 32 * B + 16 * h + 4 * q;   // first of this lane's 4 cols
        const f32x4 Ba = *reinterpret_cast<const f32x4*>(Blds + c0 * 2);
        const f32x4 Bb = *reinterpret_cast<const f32x4*>(Blds + c0 * 2 + 4);
        f32x4 o;
        o.x = fmaxf(fmaf(dd.x, Ba.x, fmaf(dd.y, Ba.y, acc[4 * h + 0] + bias)), 0.f);
        o.y = fmaxf(fmaf(dd.x, Ba.z, fmaf(dd.y, Ba.w, acc[4 * h + 1] + bias)), 0.f);
        o.z = fmaxf(fmaf(dd.x, Bb.x, fmaf(dd.y, Bb.y, acc[4 * h + 2] + bias)), 0.f);
        o.w = fmaxf(fmaf(dd.x, Bb.z, fmaf(dd.y, Bb.w, acc[4 * h + 3] + bias)), 0.f);
        __builtin_nontemporal_store(
            o, reinterpret_cast<f32x4*>(out + rbw + 32 * B + 16 * h + q * 4));
    }
}

__global__ __launch_bounds__(THREADS) void tn_kernel(
    const float* __restrict__ v,
    const float* __restrict__ dx,
    const float* __restrict__ A,
    const float* __restrict__ Bm,
    const float* __restrict__ bsc,
    float* __restrict__ out)
{
    __shared__ float Alds[NBLK * BS * BS]; // [b][kk][col] (16 KB)
    __shared__ float Blds[COLS * 2];       // B rows for 128 cols (1 KB)

    const int tid = threadIdx.x;
    const int cg  = blockIdx.x & (COLGROUPS - 1);
    const int rt  = blockIdx.x >> 5;
    const int nb0 = cg * NBLK;

    // Stage A (16 KB = 1024 f32x4): 256 threads x 4; B: 64 f32x4.
    {
        const f32x4* src = reinterpret_cast<const f32x4*>(A + nb0 * (BS * BS));
#pragma unroll
        for (int i = 0; i < 4; ++i)
            reinterpret_cast<f32x4*>(Alds)[tid + 256 * i] = src[tid + 256 * i];
        if (tid < COLS * 2 / 4)
            reinterpret_cast<f32x4*>(Blds)[tid] =
                reinterpret_cast<const f32x4*>(Bm + nb0 * (BS * 2))[tid];
    }
    __syncthreads();

    const float bias = *bsc;
    const int lane = tid & 63;
    const int wv   = tid >> 6;
    const int r    = lane >> 2;
    const int q    = lane & 3;

    const int row0 = rt * ROWS_PER_WG + wv * 16 + r;
    const size_t rb0 = (size_t)row0 * NN + nb0 * BS;
    constexpr size_t IT_STRIDE = (size_t)ROWS_PER_IT * NN;

    // 1-deep prefetch, named registers, static rotation.
    f32x4 w[8], wn[8];
    f32x2 dd, ddn;
#pragma unroll
    for (int j = 0; j < 8; ++j)
        w[j] = *reinterpret_cast<const f32x4*>(v + rb0 + j * 16 + q * 4);
    dd = *reinterpret_cast<const f32x2*>(dx + (size_t)row0 * 2);

#pragma unroll 1
    for (int it = 0; it < ITERS; ++it) {
        if (it < ITERS - 1) {
            const size_t rbn = rb0 + (size_t)(it + 1) * IT_STRIDE;
#pragma unroll
            for (int j = 0; j < 8; ++j)
                wn[j] = *reinterpret_cast<const f32x4*>(v + rbn + j * 16 + q * 4);
            ddn = *reinterpret_cast<const f32x2*>(
                      dx + (size_t)(row0 + (it + 1) * ROWS_PER_IT) * 2);
        } else {
#pragma unroll
            for (int j = 0; j < 8; ++j) wn[j] = w[j];
            ddn = dd;
        }

        const size_t rbw = rb0 + (size_t)it * IT_STRIDE;
        do_block<0>(w, Alds, Blds, q, dd, bias, out, rbw);
        do_block<1>(w, Alds, Blds, q, dd, bias, out, rbw);
        do_block<2>(w, Alds, Blds, q, dd, bias, out, rbw);
        do_block<3>(w, Alds, Blds, q, dd, bias, out, rbw);

#pragma unroll
        for (int j = 0; j < 8; ++j) w[j] = wn[j];
        dd = ddn;
    }
}

extern "C" void kernel_launch(void* const* d_in, const int* in_sizes, int n_in,
                              void* d_out, int out_size, void* d_ws, size_t ws_size,
                              hipStream_t stream) {
    const float* v  = (const float*)d_in[0];  // [16384,4096]
    const float* dx = (const float*)d_in[1];  // [16384,2]
    const float* A  = (const float*)d_in[2];  // [128,32,32]
    const float* Bm = (const float*)d_in[3];  // [4096,2]
    const float* b  = (const float*)d_in[4];  // scalar
    float* out = (float*)d_out;               // [16384,4096]

    const int grid = COLGROUPS * ROWTILES; // 32 * 64 = 2048
    tn_kernel<<<dim3(grid), dim3(THREADS), 0, stream>>>(v, dx, A, Bm, b, out);
}

// Round 12
// 89.865 us; speedup vs baseline: 1.2719x; 1.2719x over previous
//
#include <hip/hip_runtime.h>

// Problem constants (from reference)
constexpr int BATCH = 16384;
constexpr int NN    = 4096;    // NUM_NEURONS
constexpr int BS    = 32;      // BLOCK_SIZE
constexpr int NB    = NN / BS; // 128 blocks

constexpr int THREADS     = 256;   // 4 waves, each fully independent (no LDS!)
constexpr int ROWS_PER_IT = 128;   // 4 waves x 32 rows
constexpr int ROWS_PER_WG = 1024;
constexpr int ITERS       = ROWS_PER_WG / ROWS_PER_IT;  // 8
constexpr int ROWTILES    = BATCH / ROWS_PER_WG;        // 16

typedef float f32x4  __attribute__((ext_vector_type(4)));
typedef float f32x2  __attribute__((ext_vector_type(2)));
typedef float f32x16 __attribute__((ext_vector_type(16)));
typedef short s16x8  __attribute__((ext_vector_type(8)));

// MFMA route: out-tile 32(batch rows) x 32(cols) per wave-iter.
//   acc = mfma(dx_frag, Bmat_frag, 0)            // dx @ B^T (k=0,1 zero-pad)
//   acc = mfma(v_frag_k0_15,  Amat_frag_0, acc)  // v @ A, k 0..15
//   acc = mfma(v_frag_k16_31, Amat_frag_1, acc)  // v @ A, k 16..31
// A-matrix lives in REGISTERS (2x s16x8/lane, loaded once) -> zero LDS,
// zero barriers; the LDS return path (the ~109us convergence wall of
// R3/R6/R10/R11) is gone entirely.
//
// Layouts (32x32x16_bf16): A-op lane l: row=l&31, k=(l>>5)*8+e.
// B-op lane l: col=l&31, k=(l>>5)*8+e. C/D (HW-verified m74/m101):
// col=lane&31, row=(reg&3)+8*(reg>>2)+4*(lane>>5). A consistent
// k-permutation error on both operands cancels in the dot product.
//
// Hard-won rules kept: __launch_bounds__(THREADS) with no min-waves arg;
// no forced occupancy; static indexing everywhere.

__device__ __forceinline__ short bf16rne(float f) {
    const unsigned u = __float_as_uint(f);
    return (short)((u + 0x7FFFu + ((u >> 16) & 1u)) >> 16);  // round-nearest-even
}

__global__ __launch_bounds__(THREADS) void tn_kernel(
    const float* __restrict__ v,
    const float* __restrict__ dx,
    const float* __restrict__ A,
    const float* __restrict__ Bm,
    const float* __restrict__ bsc,
    float* __restrict__ out)
{
    const int tid  = threadIdx.x;
    const int nblk = blockIdx.x & (NB - 1);
    const int rt   = blockIdx.x >> 7;
    const int lane = tid & 63;
    const int wv   = tid >> 6;
    const int lr   = lane & 31;   // M (batch row) / N (col) lane index
    const int lh   = lane >> 5;   // k-octet selector

    // ---- A-matrix fragments (MFMA B-operand), loaded once per WG ----
    // afrag[kh][e] = A[nblk][kh*16 + lh*8 + e][lr] as bf16
    s16x8 afrag0, afrag1;
    {
        const float* Ab = A + nblk * (BS * BS) + lh * 8 * BS + lr;
#pragma unroll
        for (int e = 0; e < 8; ++e) {
            afrag0[e] = bf16rne(Ab[e * BS]);
            afrag1[e] = bf16rne(Ab[(16 + e) * BS]);
        }
    }

    // ---- B-matrix fragment for the dx-MFMA (constant; nonzero k=0,1) ----
    const f32x2 bm = *reinterpret_cast<const f32x2*>(Bm + (nblk * BS + lr) * 2);
    s16x8 bfrag = {0, 0, 0, 0, 0, 0, 0, 0};
    bfrag[0] = (lh == 0) ? bf16rne(bm.x) : (short)0;
    bfrag[1] = (lh == 0) ? bf16rne(bm.y) : (short)0;

    const float bias = *bsc;

    // Per-lane base pointers
    const int rowbase = rt * ROWS_PER_WG + wv * 32 + lr;            // A-op row
    const float* vb0  = v + (size_t)rowbase * NN + nblk * BS + lh * 8;
    const float* dxb  = dx + (size_t)rowbase * 2;
    // Store base: rows rt*1024 + wv*32 + 4*lh + rowoff(r), col nblk*32+lr
    float* ob = out + (size_t)(rt * ROWS_PER_WG + wv * 32 + 4 * lh) * NN
                    + nblk * BS + lr;

    constexpr size_t IT_VSTRIDE = (size_t)ROWS_PER_IT * NN;

    // 1-deep software pipeline, named registers.
    f32x4 wc[4], wn[4];
    f32x2 dc, dn;
    wc[0] = *reinterpret_cast<const f32x4*>(vb0 + 0);
    wc[1] = *reinterpret_cast<const f32x4*>(vb0 + 4);
    wc[2] = *reinterpret_cast<const f32x4*>(vb0 + 16);
    wc[3] = *reinterpret_cast<const f32x4*>(vb0 + 20);
    dc    = *reinterpret_cast<const f32x2*>(dxb);

#pragma unroll 1
    for (int it = 0; it < ITERS; ++it) {
        if (it < ITERS - 1) {
            const float* vbn = vb0 + (size_t)(it + 1) * IT_VSTRIDE;
            wn[0] = *reinterpret_cast<const f32x4*>(vbn + 0);
            wn[1] = *reinterpret_cast<const f32x4*>(vbn + 4);
            wn[2] = *reinterpret_cast<const f32x4*>(vbn + 16);
            wn[3] = *reinterpret_cast<const f32x4*>(vbn + 20);
            dn    = *reinterpret_cast<const f32x2*>(dxb + (size_t)(it + 1) * ROWS_PER_IT * 2);
        } else {
#pragma unroll
            for (int j = 0; j < 4; ++j) wn[j] = wc[j];
            dn = dc;
        }

        // Pack v to bf16 fragments (k 0..15 and 16..31)
        s16x8 vf0, vf1;
#pragma unroll
        for (int e = 0; e < 4; ++e) {
            vf0[e]     = bf16rne(wc[0][e]);
            vf0[e + 4] = bf16rne(wc[1][e]);
            vf1[e]     = bf16rne(wc[2][e]);
            vf1[e + 4] = bf16rne(wc[3][e]);
        }
        // dx fragment (nonzero k=0,1 only)
        s16x8 dxf = {0, 0, 0, 0, 0, 0, 0, 0};
        dxf[0] = (lh == 0) ? bf16rne(dc.x) : (short)0;
        dxf[1] = (lh == 0) ? bf16rne(dc.y) : (short)0;

        f32x16 acc = {0.f, 0.f, 0.f, 0.f, 0.f, 0.f, 0.f, 0.f,
                      0.f, 0.f, 0.f, 0.f, 0.f, 0.f, 0.f, 0.f};
        acc = __builtin_amdgcn_mfma_f32_32x32x16_bf16(dxf, bfrag, acc, 0, 0, 0);
        acc = __builtin_amdgcn_mfma_f32_32x32x16_bf16(vf0, afrag0, acc, 0, 0, 0);
        acc = __builtin_amdgcn_mfma_f32_32x32x16_bf16(vf1, afrag1, acc, 0, 0, 0);

        // Epilogue: bias + ReLU; each store instr writes 2 FULL 128-B lines.
        float* orow = ob + (size_t)it * IT_VSTRIDE;
#pragma unroll
        for (int r = 0; r < 16; ++r) {
            const int rowoff = (r & 3) + 8 * (r >> 2);
            const float o = fmaxf(acc[r] + bias, 0.0f);
            __builtin_nontemporal_store(o, orow + (size_t)rowoff * NN);
        }

#pragma unroll
        for (int j = 0; j < 4; ++j) wc[j] = wn[j];
        dc = dn;
    }
}

extern "C" void kernel_launch(void* const* d_in, const int* in_sizes, int n_in,
                              void* d_out, int out_size, void* d_ws, size_t ws_size,
                              hipStream_t stream) {
    const float* v  = (const float*)d_in[0];  // [16384,4096]
    const float* dx = (const float*)d_in[1];  // [16384,2]
    const float* A  = (const float*)d_in[2];  // [128,32,32]
    const float* Bm = (const float*)d_in[3];  // [4096,2]
    const float* b  = (const float*)d_in[4];  // scalar
    float* out = (float*)d_out;               // [16384,4096]

    const int grid = NB * ROWTILES; // 128 * 16 = 2048
    tn_kernel<<<dim3(grid), dim3(THREADS), 0, stream>>>(v, dx, A, Bm, b, out);
}